// Round 2
// baseline (1499.123 us; speedup 1.0000x reference)
//
#include <hip/hip_runtime.h>
#include <hip/hip_bf16.h>

typedef __hip_bfloat16 bf16;
typedef __bf16 v8bf __attribute__((ext_vector_type(8)));
typedef float f32x4 __attribute__((ext_vector_type(4)));

__device__ __forceinline__ float b2f(bf16 v) { return __bfloat162float(v); }
__device__ __forceinline__ bf16 f2b(float f) { return __float2bfloat16(f); }

// Read element i of an input tensor that is either bf16 (isbf=1) or f32.
__device__ __forceinline__ float loadf(const void* p, size_t i, int isbf) {
    if (isbf) return b2f(((const bf16*)p)[i]);
    return ((const float*)p)[i];
}

// ---------------------------------------------------------------------------
// Runtime dtype detection: ea values are uniform[0.1,1]. If the buffer is
// bf16, all of the first 64 u16 words decode (<<16) to ~[0.1,1]. If float32,
// only ~half (the truncation halves) land in range; mantissa halves are
// random bf16 patterns (~3% in range). Threshold at 60.
__global__ void detect_kernel(const void* __restrict__ ea, int* __restrict__ flag)
{
    if (threadIdx.x == 0 && blockIdx.x == 0) {
        const unsigned short* u = (const unsigned short*)ea;
        int cnt = 0;
        for (int i = 0; i < 64; i++) {
            unsigned int w = ((unsigned int)u[i]) << 16;
            float f = __uint_as_float(w);
            if (f >= 0.05f && f <= 1.05f) cnt++;
        }
        *flag = (cnt >= 60) ? 1 : 0;
    }
}

// ---------------------------------------------------------------------------
// Transpose 3 contiguous 256x256 matrices: WT[mat][n][k] = W[mat][k][n]
__global__ __launch_bounds__(256) void transpose_kernel(
    const void* __restrict__ W, bf16* __restrict__ WT, const int* __restrict__ flag)
{
    int isbf = *flag;
    int b = blockIdx.x;
    int mat = b >> 8, n = b & 255;
    int k = threadIdx.x;
    WT[(size_t)mat * 65536 + n * 256 + k] =
        f2b(loadf(W, (size_t)mat * 65536 + k * 256 + n, isbf));
}

// ---------------------------------------------------------------------------
// col_emb[j][d] = (relu(j*pW1+pb1) @ pW2 + pb2)[d]   for j in [0,1024)
__global__ __launch_bounds__(256) void col_emb_kernel(
    const void* __restrict__ pW1, const void* __restrict__ pb1,
    const void* __restrict__ pW2, const void* __restrict__ pb2,
    bf16* __restrict__ cemb, const int* __restrict__ flag)
{
    int isbf = *flag;
    int j = blockIdx.x;
    int d = threadIdx.x;
    float jf = (float)j;
    float acc = loadf(pb2, d, isbf);
    #pragma unroll
    for (int k = 0; k < 16; k++) {
        float h = fmaxf(jf * loadf(pW1, k, isbf) + loadf(pb1, k, isbf), 0.0f);
        acc += h * loadf(pW2, k * 256 + d, isbf);
    }
    cemb[(size_t)j * 256 + d] = f2b(acc);
}

// ---------------------------------------------------------------------------
// x0[n][d] = mean over nonzero cols m of init[n] of cemb[m][d] (0 if none)
__global__ __launch_bounds__(256) void projection_kernel(
    const void* __restrict__ init, const bf16* __restrict__ cemb,
    bf16* __restrict__ x0, const int* __restrict__ flag)
{
    __shared__ int idxs[1024];
    __shared__ int cnt;
    int isbf = *flag;
    int n = blockIdx.x, t = threadIdx.x;
    if (t == 0) cnt = 0;
    __syncthreads();
    if (isbf) {
        const unsigned short* row = (const unsigned short*)init + (size_t)n * 1024;
        for (int m = t; m < 1024; m += 256) {
            if ((row[m] & 0x7fffu) != 0) { int p = atomicAdd(&cnt, 1); idxs[p] = m; }
        }
    } else {
        const float* row = (const float*)init + (size_t)n * 1024;
        for (int m = t; m < 1024; m += 256) {
            if (row[m] != 0.0f) { int p = atomicAdd(&cnt, 1); idxs[p] = m; }
        }
    }
    __syncthreads();
    int c = cnt;
    float acc = 0.0f;
    for (int j = 0; j < c; j++)
        acc += b2f(cemb[(size_t)idxs[j] * 256 + t]);
    float denom = (c > 0) ? (float)c : 1.0f;
    x0[(size_t)n * 256 + t] = f2b(acc / denom);
}

// ---------------------------------------------------------------------------
__global__ void init_deg_kernel(float* __restrict__ deg, int* __restrict__ cntv, int N)
{
    int i = blockIdx.x * 256 + threadIdx.x;
    if (i < N) { deg[i] = 1.0f; cntv[i] = 0; }  // 1.0 = self-loop weight
}

__global__ void edge_deg_kernel(const int* __restrict__ ei, const void* __restrict__ ea,
                                float* __restrict__ deg, int* __restrict__ cntv, int E,
                                const int* __restrict__ flag)
{
    int isbf = *flag;
    int e = blockIdx.x * 256 + threadIdx.x;
    if (e < E) {
        int c = ei[E + e];
        atomicAdd(&deg[c], loadf(ea, e, isbf));
        atomicAdd(&cntv[c], 1);
    }
}

__global__ __launch_bounds__(1024) void scan_kernel(
    const float* __restrict__ deg, const int* __restrict__ cntv,
    int* __restrict__ col_ptr, int* __restrict__ cursor,
    float* __restrict__ dinv, float* __restrict__ nloop, int N, int E)
{
    __shared__ int s[1024];
    int t = threadIdx.x;
    const int CH = 20;  // 1024*20 >= 20000
    int i0 = t * CH;
    int sum = 0;
    for (int j = 0; j < CH; j++) { int i = i0 + j; if (i < N) sum += cntv[i]; }
    s[t] = sum;
    __syncthreads();
    for (int off = 1; off < 1024; off <<= 1) {
        int v = (t >= off) ? s[t - off] : 0;
        __syncthreads();
        s[t] += v;
        __syncthreads();
    }
    int run = s[t] - sum;  // exclusive prefix
    for (int j = 0; j < CH; j++) {
        int i = i0 + j;
        if (i < N) {
            col_ptr[i] = run;
            cursor[i] = run;
            run += cntv[i];
            float dv = rsqrtf(deg[i]);  // deg >= 1 always (self loop)
            dinv[i] = dv;
            nloop[i] = 1.0f / deg[i];
        }
    }
    if (t == 0) col_ptr[N] = E;
}

__global__ void fill_kernel(const int* __restrict__ ei, const void* __restrict__ ea,
                            const float* __restrict__ dinv, int* __restrict__ cursor,
                            int* __restrict__ srow, float* __restrict__ snorm, int E,
                            const int* __restrict__ flag)
{
    int isbf = *flag;
    int e = blockIdx.x * 256 + threadIdx.x;
    if (e < E) {
        int r = ei[e], c = ei[E + e];
        float nm = dinv[r] * loadf(ea, e, isbf) * dinv[c];
        int pos = atomicAdd(&cursor[c], 1);
        srow[pos] = r;
        snorm[pos] = nm;
    }
}

// ---------------------------------------------------------------------------
// y[i][d] = nloop[i]*x[i][d] + sum_e snorm[e]*x[srow[e]][d]  (CSR over col i)
#define AGG_CHUNK 512
__global__ __launch_bounds__(256) void aggregate_kernel(
    const bf16* __restrict__ x, bf16* __restrict__ y,
    const int* __restrict__ col_ptr, const int* __restrict__ srow,
    const float* __restrict__ snorm, const float* __restrict__ nloop)
{
    __shared__ int lrow[AGG_CHUNK];
    __shared__ float lnorm[AGG_CHUNK];
    int i = blockIdx.x;
    int d = threadIdx.x;
    int start = col_ptr[i], end = col_ptr[i + 1];
    float acc = nloop[i] * b2f(x[(size_t)i * 256 + d]);
    for (int base = start; base < end; base += AGG_CHUNK) {
        int n = min(AGG_CHUNK, end - base);
        __syncthreads();
        for (int t = d; t < n; t += 256) {
            lrow[t] = srow[base + t];
            lnorm[t] = snorm[base + t];
        }
        __syncthreads();
        #pragma unroll 4
        for (int j = 0; j < n; j++)
            acc += lnorm[j] * b2f(x[(size_t)lrow[j] * 256 + d]);
    }
    y[(size_t)i * 256 + d] = f2b(acc);
}

// ---------------------------------------------------------------------------
// xout = relu(y @ W + b).  WT[n][k] = W[k][n].  bias = full (3,256) tensor of
// the branch; layer selects the row (element offset resolved under the flag).
__global__ __launch_bounds__(256) void gemm_relu_kernel(
    const bf16* __restrict__ y, const bf16* __restrict__ WT,
    const void* __restrict__ bias_all, int layer, bf16* __restrict__ xout,
    const int* __restrict__ flag)
{
    int isbf = *flag;
    int wave = threadIdx.x >> 6;
    int lane = threadIdx.x & 63;
    int m0 = blockIdx.x * 32 + (wave >> 1) * 16;
    int n0 = (wave & 1) * 128;
    int mrow = lane & 15;
    int q = lane >> 4;

    f32x4 acc[8] = {};
    const v8bf* arow = reinterpret_cast<const v8bf*>(y + (size_t)(m0 + mrow) * 256);
    for (int k0 = 0; k0 < 256; k0 += 32) {
        v8bf a = arow[(k0 >> 3) + q];  // A[m=lane&15][k=q*8+j]
        #pragma unroll
        for (int nt = 0; nt < 8; nt++) {
            const v8bf* brow = reinterpret_cast<const v8bf*>(WT + (size_t)(n0 + nt * 16 + mrow) * 256);
            v8bf b = brow[(k0 >> 3) + q];  // B[k=q*8+j][n=lane&15]
            acc[nt] = __builtin_amdgcn_mfma_f32_16x16x32_bf16(a, b, acc[nt], 0, 0, 0);
        }
    }
    #pragma unroll
    for (int nt = 0; nt < 8; nt++) {
        int col = n0 + nt * 16 + mrow;          // C/D: col = lane&15
        float bv = loadf(bias_all, (size_t)layer * 256 + col, isbf);
        #pragma unroll
        for (int r = 0; r < 4; r++) {
            int row = m0 + q * 4 + r;           // C/D: row = (lane>>4)*4 + reg
            float v = acc[nt][r] + bv;
            xout[(size_t)row * 256 + col] = f2b(fmaxf(v, 0.0f));
        }
    }
}

// ---------------------------------------------------------------------------
// Meta-path softmax attention: wave per node. Output dtype follows flag.
__global__ __launch_bounds__(256) void attention_kernel(
    const bf16* __restrict__ e0, const bf16* __restrict__ e1, const bf16* __restrict__ e2,
    const void* __restrict__ w_att, void* __restrict__ out, int N,
    const int* __restrict__ flag)
{
    int isbf = *flag;
    int wave = threadIdx.x >> 6, lane = threadIdx.x & 63;
    int n = blockIdx.x * 4 + wave;
    if (n >= N) return;
    int d0 = lane * 4;
    float w[4], v0[4], v1[4], v2[4];
    #pragma unroll
    for (int j = 0; j < 4; j++) {
        w[j]  = loadf(w_att, d0 + j, isbf);
        v0[j] = b2f(e0[(size_t)n * 256 + d0 + j]);
        v1[j] = b2f(e1[(size_t)n * 256 + d0 + j]);
        v2[j] = b2f(e2[(size_t)n * 256 + d0 + j]);
    }
    float s0 = 0, s1 = 0, s2 = 0;
    #pragma unroll
    for (int j = 0; j < 4; j++) { s0 += v0[j] * w[j]; s1 += v1[j] * w[j]; s2 += v2[j] * w[j]; }
    for (int off = 1; off < 64; off <<= 1) {
        s0 += __shfl_xor(s0, off, 64);
        s1 += __shfl_xor(s1, off, 64);
        s2 += __shfl_xor(s2, off, 64);
    }
    float m = fmaxf(s0, fmaxf(s1, s2));
    float a0 = expf(s0 - m), a1 = expf(s1 - m), a2 = expf(s2 - m);
    float inv = 1.0f / (a0 + a1 + a2);
    a0 *= inv; a1 *= inv; a2 *= inv;
    #pragma unroll
    for (int j = 0; j < 4; j++) {
        float v = a0 * v0[j] + a1 * v1[j] + a2 * v2[j];
        if (isbf) ((bf16*)out)[(size_t)n * 256 + d0 + j] = f2b(v);
        else      ((float*)out)[(size_t)n * 256 + d0 + j] = v;
    }
}

// ---------------------------------------------------------------------------
extern "C" void kernel_launch(void* const* d_in, const int* in_sizes, int n_in,
                              void* d_out, int out_size, void* d_ws, size_t ws_size,
                              hipStream_t stream)
{
    constexpr int N = 20000, M = 1024, E = 640000, D = 256;
    (void)in_sizes; (void)n_in; (void)out_size; (void)ws_size;

    const void* init = d_in[0];
    const int*  ei[3] = {(const int*)d_in[1], (const int*)d_in[2], (const int*)d_in[3]};
    const void* ea[3] = {d_in[4], d_in[5], d_in[6]};
    const void* pW1 = d_in[7];
    const void* pb1 = d_in[8];
    const void* pW2 = d_in[9];
    const void* pb2 = d_in[10];
    const void* Wb[3] = {d_in[11], d_in[13], d_in[15]};
    const void* bb[3] = {d_in[12], d_in[14], d_in[16]};
    const void* w_att = d_in[17];

    char* ws = (char*)d_ws;
    size_t off = 0;
    auto carve = [&](size_t bytes) -> char* {
        off = (off + 255) & ~(size_t)255;
        char* p = ws + off;
        off += bytes;
        return p;
    };

    int*  flag = (int*)carve(4);
    bf16* WT   = (bf16*)carve((size_t)9 * 65536 * 2);
    bf16* cemb = (bf16*)carve((size_t)M * D * 2);
    bf16* x0   = (bf16*)carve((size_t)N * D * 2);
    bf16* xA   = (bf16*)carve((size_t)N * D * 2);
    bf16* ybuf = (bf16*)carve((size_t)N * D * 2);
    bf16* outp[3] = {(bf16*)carve((size_t)N * D * 2),
                     (bf16*)carve((size_t)N * D * 2),
                     (bf16*)carve((size_t)N * D * 2)};
    float* deg     = (float*)carve((size_t)N * 4);
    int*   cntv    = (int*)carve((size_t)N * 4);
    int*   col_ptr = (int*)carve((size_t)(N + 1) * 4);
    int*   cursor  = (int*)carve((size_t)N * 4);
    float* dinv    = (float*)carve((size_t)N * 4);
    float* nloop   = (float*)carve((size_t)N * 4);
    int*   srow    = (int*)carve((size_t)E * 4);
    float* snorm   = (float*)carve((size_t)E * 4);

    detect_kernel<<<1, 64, 0, stream>>>(ea[0], flag);

    for (int p = 0; p < 3; p++)
        transpose_kernel<<<768, 256, 0, stream>>>(Wb[p], WT + (size_t)p * 3 * 65536, flag);
    col_emb_kernel<<<M, 256, 0, stream>>>(pW1, pb1, pW2, pb2, cemb, flag);
    projection_kernel<<<N, 256, 0, stream>>>(init, cemb, x0, flag);

    for (int p = 0; p < 3; p++) {
        init_deg_kernel<<<(N + 255) / 256, 256, 0, stream>>>(deg, cntv, N);
        edge_deg_kernel<<<(E + 255) / 256, 256, 0, stream>>>(ei[p], ea[p], deg, cntv, E, flag);
        scan_kernel<<<1, 1024, 0, stream>>>(deg, cntv, col_ptr, cursor, dinv, nloop, N, E);
        fill_kernel<<<(E + 255) / 256, 256, 0, stream>>>(ei[p], ea[p], dinv, cursor, srow, snorm, E, flag);

        const bf16* xin = x0;
        for (int l = 0; l < 3; l++) {
            aggregate_kernel<<<N, 256, 0, stream>>>(xin, ybuf, col_ptr, srow, snorm, nloop);
            bf16* xo = (l == 2) ? outp[p] : xA;
            gemm_relu_kernel<<<N / 32, 256, 0, stream>>>(
                ybuf, WT + (size_t)(p * 3 + l) * 65536, bb[p], l, xo, flag);
            xin = xo;
        }
    }
    attention_kernel<<<N / 4, 256, 0, stream>>>(outp[0], outp[1], outp[2], w_att, d_out, N, flag);
}

// Round 3
// 1233.330 us; speedup vs baseline: 1.2155x; 1.2155x over previous
//
#include <hip/hip_runtime.h>
#include <hip/hip_bf16.h>

typedef __hip_bfloat16 bf16;
typedef __bf16 v8bf __attribute__((ext_vector_type(8)));
typedef float f32x4 __attribute__((ext_vector_type(4)));

constexpr int N = 20000, M = 1024, E = 640000, D = 256;
constexpr size_t SEGEL = (size_t)N * D;  // elements per activation segment

__device__ __forceinline__ float b2f(bf16 v) { return __bfloat162float(v); }
__device__ __forceinline__ bf16 f2b(float f) { return __float2bfloat16(f); }
__device__ __forceinline__ float u2f(unsigned short u) { return __uint_as_float(((unsigned)u) << 16); }
__device__ __forceinline__ unsigned short f2u(float f) { bf16 h = __float2bfloat16(f); return *(unsigned short*)&h; }
__device__ __forceinline__ float loadf(const void* p, size_t i, int isbf) {
    return isbf ? b2f(((const bf16*)p)[i]) : ((const float*)p)[i];
}

// ---------------------------------------------------------------------------
// Runtime dtype detect: ea ~ U[0.1,1]. bf16 buffer -> nearly all first 64 u16
// words decode (<<16) into [0.05,1.05]; f32 buffer -> only ~half.
__global__ void detect_kernel(const void* __restrict__ ea, int* __restrict__ flag)
{
    if (threadIdx.x == 0 && blockIdx.x == 0) {
        const unsigned short* u = (const unsigned short*)ea;
        int cnt = 0;
        for (int i = 0; i < 64; i++) {
            float f = __uint_as_float(((unsigned)u[i]) << 16);
            if (f >= 0.05f && f <= 1.05f) cnt++;
        }
        *flag = (cnt >= 60) ? 1 : 0;
    }
}

// ---------------------------------------------------------------------------
// Transpose all 9 256x256 weight matrices: WT[mat][n][k] = W[branch][lm][k][n]
__global__ __launch_bounds__(256) void transpose_kernel(
    const void* __restrict__ W0, const void* __restrict__ W1, const void* __restrict__ W2,
    bf16* __restrict__ WT, const int* __restrict__ flag)
{
    int isbf = *flag;
    int b = blockIdx.x;                 // 0..2303
    int mat = b >> 8, n = b & 255, k = threadIdx.x;
    const void* W = (mat < 3) ? W0 : (mat < 6) ? W1 : W2;
    int lm = mat - (mat < 3 ? 0 : (mat < 6 ? 3 : 6));
    WT[(size_t)mat * 65536 + n * 256 + k] =
        f2b(loadf(W, (size_t)lm * 65536 + k * 256 + n, isbf));
}

// ---------------------------------------------------------------------------
// cembT[d][j] = (relu(j*pW1+pb1) @ pW2 + pb2)[d]   (transposed col-emb table)
__global__ __launch_bounds__(256) void col_embT_kernel(
    const void* __restrict__ pW1, const void* __restrict__ pb1,
    const void* __restrict__ pW2, const void* __restrict__ pb2,
    bf16* __restrict__ cembT, const int* __restrict__ flag)
{
    int isbf = *flag;
    int j = blockIdx.y * 256 + threadIdx.x;   // 0..1023
    int d = blockIdx.x;                       // 0..255
    float jf = (float)j;
    float acc = loadf(pb2, d, isbf);
    #pragma unroll
    for (int k = 0; k < 16; k++) {
        float h = fmaxf(jf * loadf(pW1, k, isbf) + loadf(pb1, k, isbf), 0.0f);
        acc += h * loadf(pW2, k * 256 + d, isbf);
    }
    cembT[(size_t)d * 1024 + j] = f2b(acc);
}

// ---------------------------------------------------------------------------
// x0 = (mask(init) @ col_emb) / max(cnt,1)  as a 20000x1024x256 bf16 MFMA GEMM.
// Mask fragments built in registers; per-row nnz counted in-register.
__global__ __launch_bounds__(256) void proj_gemm_kernel(
    const void* __restrict__ init, const bf16* __restrict__ cembT,
    bf16* __restrict__ x0, const int* __restrict__ flag)
{
    int isbf = *flag;
    int wave = threadIdx.x >> 6, lane = threadIdx.x & 63;
    int m0 = blockIdx.x * 32 + (wave >> 1) * 16;
    int n0 = (wave & 1) * 128;
    int mrow = lane & 15, q = lane >> 4;
    f32x4 acc[8] = {};
    float cnt = 0.0f;
    for (int k0 = 0; k0 < 1024; k0 += 32) {
        int kb = k0 + q * 8;
        v8bf a;
        if (isbf) {
            const unsigned short* ar = (const unsigned short*)init + (size_t)(m0 + mrow) * 1024 + kb;
            ushort4 lo = *(const ushort4*)ar;
            ushort4 hi = *(const ushort4*)(ar + 4);
            unsigned short wv[8] = {lo.x, lo.y, lo.z, lo.w, hi.x, hi.y, hi.z, hi.w};
            #pragma unroll
            for (int j = 0; j < 8; j++) {
                bool nz = (wv[j] & 0x7fffu) != 0;
                a[j] = nz ? (__bf16)1.0f : (__bf16)0.0f;
                cnt += nz ? 1.0f : 0.0f;
            }
        } else {
            const float* ar = (const float*)init + (size_t)(m0 + mrow) * 1024 + kb;
            float4 lo = *(const float4*)ar;
            float4 hi = *(const float4*)(ar + 4);
            float wv[8] = {lo.x, lo.y, lo.z, lo.w, hi.x, hi.y, hi.z, hi.w};
            #pragma unroll
            for (int j = 0; j < 8; j++) {
                bool nz = wv[j] != 0.0f;
                a[j] = nz ? (__bf16)1.0f : (__bf16)0.0f;
                cnt += nz ? 1.0f : 0.0f;
            }
        }
        #pragma unroll
        for (int nt = 0; nt < 8; nt++) {
            const v8bf* brow = (const v8bf*)(cembT + (size_t)(n0 + nt * 16 + mrow) * 1024);
            acc[nt] = __builtin_amdgcn_mfma_f32_16x16x32_bf16(a, brow[kb >> 3], acc[nt], 0, 0, 0);
        }
    }
    // full row count: sum the 4 q-slices of the same mrow
    cnt += __shfl_xor(cnt, 16, 64);
    cnt += __shfl_xor(cnt, 32, 64);
    float rinv[4];
    #pragma unroll
    for (int r = 0; r < 4; r++) {
        float c = __shfl(cnt, q * 4 + r, 64);   // lane (q*4+r) holds row q*4+r
        rinv[r] = 1.0f / fmaxf(c, 1.0f);
    }
    #pragma unroll
    for (int nt = 0; nt < 8; nt++) {
        int col = n0 + nt * 16 + mrow;
        #pragma unroll
        for (int r = 0; r < 4; r++) {
            int row = m0 + q * 4 + r;
            x0[(size_t)row * 256 + col] = f2b(acc[nt][r] * rinv[r]);
        }
    }
}

// ---------------------------------------------------------------------------
// Graph setup (nb branches in one pass; serial mode launches with 1 branch)
__global__ void init_deg_kernel(float* __restrict__ deg, int* __restrict__ cntv, int total)
{
    int i = blockIdx.x * 256 + threadIdx.x;
    if (i < total) { deg[i] = 1.0f; cntv[i] = 0; }  // 1.0 = self-loop weight
}

__global__ void edge_deg_kernel(
    const int* __restrict__ e0, const int* __restrict__ e1, const int* __restrict__ e2,
    const void* __restrict__ a0, const void* __restrict__ a1, const void* __restrict__ a2,
    float* __restrict__ deg, int* __restrict__ cntv, const int* __restrict__ flag)
{
    int isbf = *flag;
    int pb = blockIdx.x / 2500;                       // E = 2500*256 exactly
    int e = (blockIdx.x - pb * 2500) * 256 + threadIdx.x;
    const int* ei = pb == 0 ? e0 : pb == 1 ? e1 : e2;
    const void* ea = pb == 0 ? a0 : pb == 1 ? a1 : a2;
    int c = ei[E + e];
    atomicAdd(&deg[pb * N + c], loadf(ea, e, isbf));
    atomicAdd(&cntv[pb * N + c], 1);
}

__global__ __launch_bounds__(1024) void scan_kernel(
    const float* __restrict__ deg, const int* __restrict__ cntv,
    int* __restrict__ col_ptr, int* __restrict__ cursor,
    float* __restrict__ dinv, float* __restrict__ nloop)
{
    int pb = blockIdx.x;
    int base = pb * E;
    __shared__ int s[1024];
    int t = threadIdx.x;
    const int CH = 20;  // 1024*20 >= 20000
    int i0 = t * CH;
    int sum = 0;
    for (int j = 0; j < CH; j++) { int i = i0 + j; if (i < N) sum += cntv[pb * N + i]; }
    s[t] = sum;
    __syncthreads();
    for (int off = 1; off < 1024; off <<= 1) {
        int v = (t >= off) ? s[t - off] : 0;
        __syncthreads();
        s[t] += v;
        __syncthreads();
    }
    int run = base + s[t] - sum;
    for (int j = 0; j < CH; j++) {
        int i = i0 + j;
        if (i < N) {
            col_ptr[pb * (N + 1) + i] = run;
            cursor[pb * N + i] = run;
            run += cntv[pb * N + i];
            float dg = deg[pb * N + i];      // >= 1 always
            dinv[pb * N + i] = rsqrtf(dg);
            nloop[pb * N + i] = 1.0f / dg;
        }
    }
    if (t == 0) col_ptr[pb * (N + 1) + N] = base + E;
}

__global__ void fill_kernel(
    const int* __restrict__ e0, const int* __restrict__ e1, const int* __restrict__ e2,
    const void* __restrict__ a0, const void* __restrict__ a1, const void* __restrict__ a2,
    const float* __restrict__ dinv, int* __restrict__ cursor,
    int* __restrict__ srow, float* __restrict__ snorm, const int* __restrict__ flag)
{
    int isbf = *flag;
    int pb = blockIdx.x / 2500;
    int e = (blockIdx.x - pb * 2500) * 256 + threadIdx.x;
    const int* ei = pb == 0 ? e0 : pb == 1 ? e1 : e2;
    const void* ea = pb == 0 ? a0 : pb == 1 ? a1 : a2;
    int r = ei[e], c = ei[E + e];
    float nm = dinv[pb * N + r] * loadf(ea, e, isbf) * dinv[pb * N + c];
    int pos = atomicAdd(&cursor[pb * N + c], 1);
    srow[pos] = r;
    snorm[pos] = nm;
}

// ---------------------------------------------------------------------------
// Wave-per-node aggregation: lane covers 4 d's (8B loads, 512B/wave gather).
// Edge (row,weight) loaded per-lane in 64-chunks, broadcast via shfl.
__global__ __launch_bounds__(256) void aggregate_kernel(
    const bf16* __restrict__ xi0, const bf16* __restrict__ xi1, const bf16* __restrict__ xi2,
    bf16* __restrict__ yb,
    const int* __restrict__ col_ptr, const int* __restrict__ srow,
    const float* __restrict__ snorm, const float* __restrict__ nloop)
{
    int wave = threadIdx.x >> 6, lane = threadIdx.x & 63;
    int pb = blockIdx.x / 5000;
    int i = (blockIdx.x - pb * 5000) * 4 + wave;
    const bf16* x = pb == 0 ? xi0 : pb == 1 ? xi1 : xi2;
    const unsigned short* xr = (const unsigned short*)x;
    int d0 = lane * 4;
    int start = col_ptr[pb * (N + 1) + i];
    int end   = col_ptr[pb * (N + 1) + i + 1];
    float nl = nloop[pb * N + i];
    ushort4 sv = *(const ushort4*)(xr + ((size_t)i << 8) + d0);
    float a0 = nl * u2f(sv.x), a1 = nl * u2f(sv.y), a2 = nl * u2f(sv.z), a3 = nl * u2f(sv.w);
    for (int base = start; base < end; base += 64) {
        int n = end - base; n = n < 64 ? n : 64;
        int r = 0; float w = 0.0f;
        if (lane < n) { r = srow[base + lane]; w = snorm[base + lane]; }
        #pragma unroll 8
        for (int j = 0; j < n; j++) {
            int rj = __shfl(r, j, 64);
            float wj = __shfl(w, j, 64);
            ushort4 v = *(const ushort4*)(xr + ((size_t)rj << 8) + d0);
            a0 = fmaf(wj, u2f(v.x), a0);
            a1 = fmaf(wj, u2f(v.y), a1);
            a2 = fmaf(wj, u2f(v.z), a2);
            a3 = fmaf(wj, u2f(v.w), a3);
        }
    }
    ushort4 o; o.x = f2u(a0); o.y = f2u(a1); o.z = f2u(a2); o.w = f2u(a3);
    *(ushort4*)((unsigned short*)yb + (size_t)pb * SEGEL + ((size_t)i << 8) + d0) = o;
}

// ---------------------------------------------------------------------------
// xout = relu(y @ W + b).  WT[n][k] = W[k][n].  Handles nb branch slices.
__global__ __launch_bounds__(256) void gemm_relu_kernel(
    const bf16* __restrict__ yb, const bf16* __restrict__ WT, int layer,
    const void* __restrict__ b0, const void* __restrict__ b1, const void* __restrict__ b2,
    bf16* __restrict__ o0, bf16* __restrict__ o1, bf16* __restrict__ o2,
    const int* __restrict__ flag, int p_base)
{
    int isbf = *flag;
    int pl = blockIdx.x / 625, blk = blockIdx.x - pl * 625;
    int p = p_base + pl;
    const bf16* y = yb + (size_t)pl * SEGEL;
    const bf16* wt = WT + (size_t)(p * 3 + layer) * 65536;
    const void* bias = p == 0 ? b0 : p == 1 ? b1 : b2;
    bf16* xout = pl == 0 ? o0 : pl == 1 ? o1 : o2;

    int wave = threadIdx.x >> 6, lane = threadIdx.x & 63;
    int m0 = blk * 32 + (wave >> 1) * 16;
    int n0 = (wave & 1) * 128;
    int mrow = lane & 15, q = lane >> 4;

    f32x4 acc[8] = {};
    const v8bf* arow = reinterpret_cast<const v8bf*>(y + (size_t)(m0 + mrow) * 256);
    for (int k0 = 0; k0 < 256; k0 += 32) {
        v8bf a = arow[(k0 >> 3) + q];
        #pragma unroll
        for (int nt = 0; nt < 8; nt++) {
            const v8bf* brow = reinterpret_cast<const v8bf*>(wt + (size_t)(n0 + nt * 16 + mrow) * 256);
            acc[nt] = __builtin_amdgcn_mfma_f32_16x16x32_bf16(a, brow[(k0 >> 3) + q], acc[nt], 0, 0, 0);
        }
    }
    #pragma unroll
    for (int nt = 0; nt < 8; nt++) {
        int col = n0 + nt * 16 + mrow;
        float bv = loadf(bias, (size_t)layer * 256 + col, isbf);
        #pragma unroll
        for (int r = 0; r < 4; r++) {
            int row = m0 + q * 4 + r;
            xout[(size_t)row * 256 + col] = f2b(fmaxf(acc[nt][r] + bv, 0.0f));
        }
    }
}

// ---------------------------------------------------------------------------
// Meta-path softmax attention: wave per node.
__global__ __launch_bounds__(256) void attention_kernel(
    const bf16* __restrict__ e0, const bf16* __restrict__ e1, const bf16* __restrict__ e2,
    const void* __restrict__ w_att, void* __restrict__ out, int n_nodes,
    const int* __restrict__ flag)
{
    int isbf = *flag;
    int wave = threadIdx.x >> 6, lane = threadIdx.x & 63;
    int n = blockIdx.x * 4 + wave;
    if (n >= n_nodes) return;
    int d0 = lane * 4;
    float w[4], v0[4], v1[4], v2[4];
    #pragma unroll
    for (int j = 0; j < 4; j++) {
        w[j]  = loadf(w_att, d0 + j, isbf);
        v0[j] = b2f(e0[(size_t)n * 256 + d0 + j]);
        v1[j] = b2f(e1[(size_t)n * 256 + d0 + j]);
        v2[j] = b2f(e2[(size_t)n * 256 + d0 + j]);
    }
    float s0 = 0, s1 = 0, s2 = 0;
    #pragma unroll
    for (int j = 0; j < 4; j++) { s0 += v0[j] * w[j]; s1 += v1[j] * w[j]; s2 += v2[j] * w[j]; }
    for (int off = 1; off < 64; off <<= 1) {
        s0 += __shfl_xor(s0, off, 64);
        s1 += __shfl_xor(s1, off, 64);
        s2 += __shfl_xor(s2, off, 64);
    }
    float m = fmaxf(s0, fmaxf(s1, s2));
    float a0 = expf(s0 - m), a1 = expf(s1 - m), a2 = expf(s2 - m);
    float inv = 1.0f / (a0 + a1 + a2);
    a0 *= inv; a1 *= inv; a2 *= inv;
    #pragma unroll
    for (int j = 0; j < 4; j++) {
        float v = a0 * v0[j] + a1 * v1[j] + a2 * v2[j];
        if (isbf) ((bf16*)out)[(size_t)n * 256 + d0 + j] = f2b(v);
        else      ((float*)out)[(size_t)n * 256 + d0 + j] = v;
    }
}

// ---------------------------------------------------------------------------
extern "C" void kernel_launch(void* const* d_in, const int* in_sizes, int n_in,
                              void* d_out, int out_size, void* d_ws, size_t ws_size,
                              hipStream_t stream)
{
    (void)in_sizes; (void)n_in; (void)out_size;

    const void* init = d_in[0];
    const int*  ei[3] = {(const int*)d_in[1], (const int*)d_in[2], (const int*)d_in[3]};
    const void* ea[3] = {d_in[4], d_in[5], d_in[6]};
    const void* pW1 = d_in[7];
    const void* pb1 = d_in[8];
    const void* pW2 = d_in[9];
    const void* pb2 = d_in[10];
    const void* Wb[3] = {d_in[11], d_in[13], d_in[15]};
    const void* bb[3] = {d_in[12], d_in[14], d_in[16]};
    const void* w_att = d_in[17];

    // Dry-run sizing for the branch-merged schedule (~121 MB)
    size_t need3;
    {
        size_t o = 0;
        auto c = [&](size_t b) { o = (o + 255) & ~(size_t)255; o += b; };
        c(4); c((size_t)9 * 65536 * 2); c((size_t)D * M * 2); c(SEGEL * 2);
        c((size_t)3 * N * 4); c((size_t)3 * N * 4); c((size_t)3 * (N + 1) * 4);
        c((size_t)3 * N * 4); c((size_t)3 * N * 4); c((size_t)3 * N * 4);
        c((size_t)3 * E * 4); c((size_t)3 * E * 4);
        c(3 * SEGEL * 2); c(3 * SEGEL * 2); c(3 * SEGEL * 2);
        need3 = o;
    }
    const int nb = (ws_size >= need3) ? 3 : 1;  // constant across calls -> graph-safe

    char* ws = (char*)d_ws;
    size_t off = 0;
    auto carve = [&](size_t bytes) -> char* {
        off = (off + 255) & ~(size_t)255;
        char* p = ws + off; off += bytes; return p;
    };
    int*   flag  = (int*)carve(4);
    bf16*  WT    = (bf16*)carve((size_t)9 * 65536 * 2);
    bf16*  cembT = (bf16*)carve((size_t)D * M * 2);
    bf16*  x0    = (bf16*)carve(SEGEL * 2);
    float* deg   = (float*)carve((size_t)nb * N * 4);
    int*   cntv  = (int*)carve((size_t)nb * N * 4);
    int*   colp  = (int*)carve((size_t)nb * (N + 1) * 4);
    int*   cursor= (int*)carve((size_t)nb * N * 4);
    float* dinv  = (float*)carve((size_t)nb * N * 4);
    float* nloop = (float*)carve((size_t)nb * N * 4);
    int*   srow  = (int*)carve((size_t)nb * E * 4);
    float* snorm = (float*)carve((size_t)nb * E * 4);
    bf16*  ybuf  = (bf16*)carve((size_t)nb * SEGEL * 2);
    bf16*  bufA  = (bf16*)carve((size_t)nb * SEGEL * 2);
    bf16*  bufB  = (bf16*)carve((size_t)3 * SEGEL * 2);

    detect_kernel<<<1, 64, 0, stream>>>(ea[0], flag);
    transpose_kernel<<<2304, 256, 0, stream>>>(Wb[0], Wb[1], Wb[2], WT, flag);
    col_embT_kernel<<<dim3(256, 4), 256, 0, stream>>>(pW1, pb1, pW2, pb2, cembT, flag);
    proj_gemm_kernel<<<625, 256, 0, stream>>>(init, cembT, x0, flag);

    if (nb == 3) {
        init_deg_kernel<<<(3 * N + 255) / 256, 256, 0, stream>>>(deg, cntv, 3 * N);
        edge_deg_kernel<<<7500, 256, 0, stream>>>(ei[0], ei[1], ei[2], ea[0], ea[1], ea[2],
                                                  deg, cntv, flag);
        scan_kernel<<<3, 1024, 0, stream>>>(deg, cntv, colp, cursor, dinv, nloop);
        fill_kernel<<<7500, 256, 0, stream>>>(ei[0], ei[1], ei[2], ea[0], ea[1], ea[2],
                                              dinv, cursor, srow, snorm, flag);
        const bf16 *i0 = x0, *i1 = x0, *i2 = x0;
        bf16* dsts[3] = {bufA, bufB, bufA};
        for (int l = 0; l < 3; l++) {
            aggregate_kernel<<<15000, 256, 0, stream>>>(i0, i1, i2, ybuf, colp, srow, snorm, nloop);
            bf16* dst = dsts[l];
            gemm_relu_kernel<<<1875, 256, 0, stream>>>(ybuf, WT, l, bb[0], bb[1], bb[2],
                                                       dst, dst + SEGEL, dst + 2 * SEGEL, flag, 0);
            i0 = dst; i1 = dst + SEGEL; i2 = dst + 2 * SEGEL;
        }
        attention_kernel<<<5000, 256, 0, stream>>>(bufA, bufA + SEGEL, bufA + 2 * SEGEL,
                                                   w_att, d_out, N, flag);
    } else {
        for (int p = 0; p < 3; p++) {
            init_deg_kernel<<<(N + 255) / 256, 256, 0, stream>>>(deg, cntv, N);
            edge_deg_kernel<<<2500, 256, 0, stream>>>(ei[p], ei[p], ei[p], ea[p], ea[p], ea[p],
                                                      deg, cntv, flag);
            scan_kernel<<<1, 1024, 0, stream>>>(deg, cntv, colp, cursor, dinv, nloop);
            fill_kernel<<<2500, 256, 0, stream>>>(ei[p], ei[p], ei[p], ea[p], ea[p], ea[p],
                                                  dinv, cursor, srow, snorm, flag);
            const bf16* xin = x0;
            for (int l = 0; l < 3; l++) {
                aggregate_kernel<<<5000, 256, 0, stream>>>(xin, xin, xin, ybuf, colp, srow, snorm, nloop);
                bf16* xo = (l == 2) ? (bufB + (size_t)p * SEGEL) : bufA;
                gemm_relu_kernel<<<625, 256, 0, stream>>>(ybuf, WT, l, bb[0], bb[1], bb[2],
                                                          xo, xo, xo, flag, p);
                xin = xo;
            }
        }
        attention_kernel<<<5000, 256, 0, stream>>>(bufB, bufB + SEGEL, bufB + 2 * SEGEL,
                                                   w_att, d_out, N, flag);
    }
}

// Round 4
// 969.487 us; speedup vs baseline: 1.5463x; 1.2721x over previous
//
#include <hip/hip_runtime.h>
#include <hip/hip_bf16.h>

typedef __hip_bfloat16 bf16;
typedef __bf16 v8bf __attribute__((ext_vector_type(8)));
typedef float f32x4 __attribute__((ext_vector_type(4)));

constexpr int N = 20000, M = 1024, E = 640000, D = 256;
constexpr size_t SEGEL = (size_t)N * D;
constexpr int NCHUNK = 10000;   // nodes per fill/count chunk (40KB LDS)
constexpr int NSLICE = 64;      // edge slices per (branch,chunk)
constexpr int ESLICE = E / NSLICE;  // 10000

__device__ __forceinline__ float b2f(bf16 v) { return __bfloat162float(v); }
__device__ __forceinline__ bf16 f2b(float f) { return __float2bfloat16(f); }
__device__ __forceinline__ float u2f(unsigned short u) { return __uint_as_float(((unsigned)u) << 16); }
__device__ __forceinline__ unsigned short f2u(float f) { bf16 h = __float2bfloat16(f); return *(unsigned short*)&h; }
__device__ __forceinline__ float loadf(const void* p, size_t i, int isbf) {
    return isbf ? b2f(((const bf16*)p)[i]) : ((const float*)p)[i];
}
__device__ __forceinline__ void fma8(float* acc, uint4 v, float w) {
    acc[0] = fmaf(w, u2f((unsigned short)(v.x & 0xffffu)), acc[0]);
    acc[1] = fmaf(w, u2f((unsigned short)(v.x >> 16)), acc[1]);
    acc[2] = fmaf(w, u2f((unsigned short)(v.y & 0xffffu)), acc[2]);
    acc[3] = fmaf(w, u2f((unsigned short)(v.y >> 16)), acc[3]);
    acc[4] = fmaf(w, u2f((unsigned short)(v.z & 0xffffu)), acc[4]);
    acc[5] = fmaf(w, u2f((unsigned short)(v.z >> 16)), acc[5]);
    acc[6] = fmaf(w, u2f((unsigned short)(v.w & 0xffffu)), acc[6]);
    acc[7] = fmaf(w, u2f((unsigned short)(v.w >> 16)), acc[7]);
}
__device__ __forceinline__ unsigned pack2(float a, float b) {
    return (unsigned)f2u(a) | ((unsigned)f2u(b) << 16);
}

// ---------------------------------------------------------------------------
__global__ void detect_kernel(const void* __restrict__ ea, int* __restrict__ flag)
{
    if (threadIdx.x == 0 && blockIdx.x == 0) {
        const unsigned short* u = (const unsigned short*)ea;
        int cnt = 0;
        for (int i = 0; i < 64; i++) {
            float f = __uint_as_float(((unsigned)u[i]) << 16);
            if (f >= 0.05f && f <= 1.05f) cnt++;
        }
        *flag = (cnt >= 60) ? 1 : 0;
    }
}

// ---------------------------------------------------------------------------
__global__ __launch_bounds__(256) void transpose_kernel(
    const void* __restrict__ W0, const void* __restrict__ W1, const void* __restrict__ W2,
    bf16* __restrict__ WT, const int* __restrict__ flag)
{
    int isbf = *flag;
    int b = blockIdx.x;                 // 0..2303
    int mat = b >> 8, n = b & 255, k = threadIdx.x;
    const void* W = (mat < 3) ? W0 : (mat < 6) ? W1 : W2;
    int lm = mat - (mat < 3 ? 0 : (mat < 6 ? 3 : 6));
    WT[(size_t)mat * 65536 + n * 256 + k] =
        f2b(loadf(W, (size_t)lm * 65536 + k * 256 + n, isbf));
}

// ---------------------------------------------------------------------------
__global__ __launch_bounds__(256) void col_embT_kernel(
    const void* __restrict__ pW1, const void* __restrict__ pb1,
    const void* __restrict__ pW2, const void* __restrict__ pb2,
    bf16* __restrict__ cembT, const int* __restrict__ flag)
{
    int isbf = *flag;
    int j = blockIdx.y * 256 + threadIdx.x;
    int d = blockIdx.x;
    float jf = (float)j;
    float acc = loadf(pb2, d, isbf);
    #pragma unroll
    for (int k = 0; k < 16; k++) {
        float h = fmaxf(jf * loadf(pW1, k, isbf) + loadf(pb1, k, isbf), 0.0f);
        acc += h * loadf(pW2, k * 256 + d, isbf);
    }
    cembT[(size_t)d * 1024 + j] = f2b(acc);
}

// ---------------------------------------------------------------------------
__global__ __launch_bounds__(256) void proj_gemm_kernel(
    const void* __restrict__ init, const bf16* __restrict__ cembT,
    bf16* __restrict__ x0, const int* __restrict__ flag)
{
    int isbf = *flag;
    int wave = threadIdx.x >> 6, lane = threadIdx.x & 63;
    int m0 = blockIdx.x * 32 + (wave >> 1) * 16;
    int n0 = (wave & 1) * 128;
    int mrow = lane & 15, q = lane >> 4;
    f32x4 acc[8] = {};
    float cnt = 0.0f;
    for (int k0 = 0; k0 < 1024; k0 += 32) {
        int kb = k0 + q * 8;
        v8bf a;
        if (isbf) {
            const unsigned short* ar = (const unsigned short*)init + (size_t)(m0 + mrow) * 1024 + kb;
            ushort4 lo = *(const ushort4*)ar;
            ushort4 hi = *(const ushort4*)(ar + 4);
            unsigned short wv[8] = {lo.x, lo.y, lo.z, lo.w, hi.x, hi.y, hi.z, hi.w};
            #pragma unroll
            for (int j = 0; j < 8; j++) {
                bool nz = (wv[j] & 0x7fffu) != 0;
                a[j] = nz ? (__bf16)1.0f : (__bf16)0.0f;
                cnt += nz ? 1.0f : 0.0f;
            }
        } else {
            const float* ar = (const float*)init + (size_t)(m0 + mrow) * 1024 + kb;
            float4 lo = *(const float4*)ar;
            float4 hi = *(const float4*)(ar + 4);
            float wv[8] = {lo.x, lo.y, lo.z, lo.w, hi.x, hi.y, hi.z, hi.w};
            #pragma unroll
            for (int j = 0; j < 8; j++) {
                bool nz = wv[j] != 0.0f;
                a[j] = nz ? (__bf16)1.0f : (__bf16)0.0f;
                cnt += nz ? 1.0f : 0.0f;
            }
        }
        #pragma unroll
        for (int nt = 0; nt < 8; nt++) {
            const v8bf* brow = (const v8bf*)(cembT + (size_t)(n0 + nt * 16 + mrow) * 1024);
            acc[nt] = __builtin_amdgcn_mfma_f32_16x16x32_bf16(a, brow[kb >> 3], acc[nt], 0, 0, 0);
        }
    }
    cnt += __shfl_xor(cnt, 16, 64);
    cnt += __shfl_xor(cnt, 32, 64);
    float rinv[4];
    #pragma unroll
    for (int r = 0; r < 4; r++) {
        float c = __shfl(cnt, q * 4 + r, 64);
        rinv[r] = 1.0f / fmaxf(c, 1.0f);
    }
    #pragma unroll
    for (int nt = 0; nt < 8; nt++) {
        int col = n0 + nt * 16 + mrow;
        #pragma unroll
        for (int r = 0; r < 4; r++) {
            int row = m0 + q * 4 + r;
            x0[(size_t)row * 256 + col] = f2b(acc[nt][r] * rinv[r]);
        }
    }
}

// ---------------------------------------------------------------------------
// Atomic-free CSR build: per-(branch,chunk,slice) LDS histograms.
// P[pb][s][c] partial counts; grid 3*2*64 = 384 blocks.
__global__ __launch_bounds__(256) void countP_kernel(
    const int* __restrict__ e0, const int* __restrict__ e1, const int* __restrict__ e2,
    int* __restrict__ P)
{
    __shared__ int cur[NCHUNK];
    int b = blockIdx.x;
    int pb = b >> 7, rem = b & 127;
    int ck = rem >> 6, s = rem & 63;
    const int* ei = pb == 0 ? e0 : pb == 1 ? e1 : e2;
    int c0 = ck * NCHUNK;
    int t = threadIdx.x;
    for (int i = t; i < NCHUNK; i += 256) cur[i] = 0;
    __syncthreads();
    int ebase = s * ESLICE;
    for (int e = ebase + t; e < ebase + ESLICE; e += 256) {
        int c = ei[E + e];
        if (c >= c0 && c < c0 + NCHUNK) atomicAdd(&cur[c - c0], 1);
    }
    __syncthreads();
    int* Prow = P + ((size_t)(pb * NSLICE + s)) * N + c0;
    for (int i = t; i < NCHUNK; i += 256) Prow[i] = cur[i];
}

// cnt[pb][c] = sum over slices of P
__global__ __launch_bounds__(256) void cnt_sum_kernel(
    const int* __restrict__ P, int* __restrict__ cnt)
{
    int id = blockIdx.x * 256 + threadIdx.x;
    if (id >= 3 * N) return;
    int pb = id / N, c = id - pb * N;
    int sum = 0;
    #pragma unroll 8
    for (int s = 0; s < NSLICE; s++)
        sum += P[((size_t)(pb * NSLICE + s)) * N + c];
    cnt[id] = sum;
}

// col_ptr prefix-sum per branch (1 block per branch), base pb*E included.
__global__ __launch_bounds__(1024) void scan_kernel(
    const int* __restrict__ cnt, int* __restrict__ col_ptr)
{
    int pb = blockIdx.x;
    int base = pb * E;
    __shared__ int s[1024];
    int t = threadIdx.x;
    const int CH = 20;
    int i0 = t * CH;
    int sum = 0;
    for (int j = 0; j < CH; j++) { int i = i0 + j; if (i < N) sum += cnt[pb * N + i]; }
    s[t] = sum;
    __syncthreads();
    for (int off = 1; off < 1024; off <<= 1) {
        int v = (t >= off) ? s[t - off] : 0;
        __syncthreads();
        s[t] += v;
        __syncthreads();
    }
    int run = base + s[t] - sum;
    for (int j = 0; j < CH; j++) {
        int i = i0 + j;
        if (i < N) {
            col_ptr[pb * (N + 1) + i] = run;
            run += cnt[pb * N + i];
        }
    }
    if (t == 0) col_ptr[pb * (N + 1) + N] = base + E;
}

// Convert P in place into per-slice start offsets (colp + exclusive scan).
__global__ __launch_bounds__(256) void base_kernel(
    int* __restrict__ P, const int* __restrict__ col_ptr)
{
    int id = blockIdx.x * 256 + threadIdx.x;
    if (id >= 3 * N) return;
    int pb = id / N, c = id - pb * N;
    int run = col_ptr[pb * (N + 1) + c];
    for (int s = 0; s < NSLICE; s++) {
        size_t idx = ((size_t)(pb * NSLICE + s)) * N + c;
        int v = P[idx];
        P[idx] = run;
        run += v;
    }
}

// Place edges: (srow, w_raw) at deterministic slice base + LDS cursor rank.
__global__ __launch_bounds__(256) void fill_kernel(
    const int* __restrict__ e0, const int* __restrict__ e1, const int* __restrict__ e2,
    const void* __restrict__ a0, const void* __restrict__ a1, const void* __restrict__ a2,
    const int* __restrict__ P, int* __restrict__ srow, float* __restrict__ swv,
    const int* __restrict__ flag)
{
    __shared__ int cur[NCHUNK];
    int isbf = *flag;
    int b = blockIdx.x;
    int pb = b >> 7, rem = b & 127;
    int ck = rem >> 6, s = rem & 63;
    const int* ei = pb == 0 ? e0 : pb == 1 ? e1 : e2;
    const void* ea = pb == 0 ? a0 : pb == 1 ? a1 : a2;
    int c0 = ck * NCHUNK;
    int t = threadIdx.x;
    const int* Prow = P + ((size_t)(pb * NSLICE + s)) * N + c0;
    for (int i = t; i < NCHUNK; i += 256) cur[i] = Prow[i];
    __syncthreads();
    int ebase = s * ESLICE;
    for (int e = ebase + t; e < ebase + ESLICE; e += 256) {
        int c = ei[E + e];
        if (c >= c0 && c < c0 + NCHUNK) {
            int r = ei[e];
            float w = loadf(ea, e, isbf);
            int pos = atomicAdd(&cur[c - c0], 1);
            srow[pos] = r;
            swv[pos] = w;
        }
    }
}

// deg = 1 + sum(w_raw) per node -> dinv, nloop  (wave per node)
__global__ __launch_bounds__(256) void degsum_kernel(
    const int* __restrict__ col_ptr, const float* __restrict__ swv,
    float* __restrict__ dinv, float* __restrict__ nloop)
{
    int wave = threadIdx.x >> 6, lane = threadIdx.x & 63;
    int pb = blockIdx.x / 5000;
    int i = (blockIdx.x - pb * 5000) * 4 + wave;
    int start = col_ptr[pb * (N + 1) + i], end = col_ptr[pb * (N + 1) + i + 1];
    float sum = 0.0f;
    for (int p = start + lane; p < end; p += 64) sum += swv[p];
    for (int off = 1; off < 64; off <<= 1) sum += __shfl_xor(sum, off, 64);
    if (lane == 0) {
        float dg = 1.0f + sum;
        dinv[pb * N + i] = rsqrtf(dg);
        nloop[pb * N + i] = 1.0f / dg;
    }
}

// swv[pos] = dinv[c] * w_raw * dinv[r]  (in place; wave per node)
__global__ __launch_bounds__(256) void snorm_kernel(
    const int* __restrict__ col_ptr, const int* __restrict__ srow,
    float* __restrict__ swv, const float* __restrict__ dinv)
{
    int wave = threadIdx.x >> 6, lane = threadIdx.x & 63;
    int pb = blockIdx.x / 5000;
    int i = (blockIdx.x - pb * 5000) * 4 + wave;
    int start = col_ptr[pb * (N + 1) + i], end = col_ptr[pb * (N + 1) + i + 1];
    float dc = dinv[pb * N + i];
    for (int p = start + lane; p < end; p += 64) {
        int r = srow[p];
        swv[p] = dc * swv[p] * dinv[pb * N + r];
    }
}

// ---------------------------------------------------------------------------
// Wave-per-node aggregation; half-wave per edge, 16B loads per lane.
__global__ __launch_bounds__(256) void aggregate_kernel(
    const bf16* __restrict__ xi0, const bf16* __restrict__ xi1, const bf16* __restrict__ xi2,
    bf16* __restrict__ yb,
    const int* __restrict__ col_ptr, const int* __restrict__ srow,
    const float* __restrict__ snorm, const float* __restrict__ nloop)
{
    int wave = threadIdx.x >> 6, lane = threadIdx.x & 63;
    int pb = blockIdx.x / 5000;
    int i = (blockIdx.x - pb * 5000) * 4 + wave;
    const bf16* x = pb == 0 ? xi0 : pb == 1 ? xi1 : xi2;
    const uint4* xr = (const uint4*)x;           // 32 uint4 per row
    int L = lane & 31, h = lane >> 5;
    int start = col_ptr[pb * (N + 1) + i], end = col_ptr[pb * (N + 1) + i + 1];
    float nl = nloop[pb * N + i];
    float acc[8];
    {
        uint4 sv = xr[(size_t)i * 32 + L];
        float self = (h == 0) ? nl : 0.0f;
        #pragma unroll
        for (int j = 0; j < 8; j++) acc[j] = 0.0f;
        fma8(acc, sv, self);
    }
    for (int base = start; base < end; base += 64) {
        int n = end - base; n = n < 64 ? n : 64;
        int r = 0; float w = 0.0f;
        if (lane < n) { r = srow[base + lane]; w = snorm[base + lane]; }
        #pragma unroll 4
        for (int jj = 0; jj < n; jj += 2) {
            int rj = __shfl(r, jj + h, 64);       // jj+h==n hits a w=0 lane: safe
            float wj = __shfl(w, jj + h, 64);
            uint4 v = xr[(size_t)rj * 32 + L];
            fma8(acc, v, wj);
        }
    }
    #pragma unroll
    for (int j = 0; j < 8; j++) acc[j] += __shfl_xor(acc[j], 32, 64);
    if (h == 0) {
        uint4 o;
        o.x = pack2(acc[0], acc[1]);
        o.y = pack2(acc[2], acc[3]);
        o.z = pack2(acc[4], acc[5]);
        o.w = pack2(acc[6], acc[7]);
        ((uint4*)yb)[(size_t)pb * (SEGEL / 8) + (size_t)i * 32 + L] = o;
    }
}

// ---------------------------------------------------------------------------
__global__ __launch_bounds__(256) void gemm_relu_kernel(
    const bf16* __restrict__ yb, const bf16* __restrict__ WT, int layer,
    const void* __restrict__ b0, const void* __restrict__ b1, const void* __restrict__ b2,
    bf16* __restrict__ o0, bf16* __restrict__ o1, bf16* __restrict__ o2,
    const int* __restrict__ flag)
{
    int isbf = *flag;
    int pl = blockIdx.x / 625, blk = blockIdx.x - pl * 625;
    const bf16* y = yb + (size_t)pl * SEGEL;
    const bf16* wt = WT + (size_t)(pl * 3 + layer) * 65536;
    const void* bias = pl == 0 ? b0 : pl == 1 ? b1 : b2;
    bf16* xout = pl == 0 ? o0 : pl == 1 ? o1 : o2;

    int wave = threadIdx.x >> 6, lane = threadIdx.x & 63;
    int m0 = blk * 32 + (wave >> 1) * 16;
    int n0 = (wave & 1) * 128;
    int mrow = lane & 15, q = lane >> 4;

    f32x4 acc[8] = {};
    const v8bf* arow = reinterpret_cast<const v8bf*>(y + (size_t)(m0 + mrow) * 256);
    for (int k0 = 0; k0 < 256; k0 += 32) {
        v8bf a = arow[(k0 >> 3) + q];
        #pragma unroll
        for (int nt = 0; nt < 8; nt++) {
            const v8bf* brow = reinterpret_cast<const v8bf*>(wt + (size_t)(n0 + nt * 16 + mrow) * 256);
            acc[nt] = __builtin_amdgcn_mfma_f32_16x16x32_bf16(a, brow[(k0 >> 3) + q], acc[nt], 0, 0, 0);
        }
    }
    #pragma unroll
    for (int nt = 0; nt < 8; nt++) {
        int col = n0 + nt * 16 + mrow;
        float bv = loadf(bias, (size_t)layer * 256 + col, isbf);
        #pragma unroll
        for (int r = 0; r < 4; r++) {
            int row = m0 + q * 4 + r;
            xout[(size_t)row * 256 + col] = f2b(fmaxf(acc[nt][r] + bv, 0.0f));
        }
    }
}

// ---------------------------------------------------------------------------
__global__ __launch_bounds__(256) void attention_kernel(
    const bf16* __restrict__ e0, const bf16* __restrict__ e1, const bf16* __restrict__ e2,
    const void* __restrict__ w_att, void* __restrict__ out, int n_nodes,
    const int* __restrict__ flag)
{
    int isbf = *flag;
    int wave = threadIdx.x >> 6, lane = threadIdx.x & 63;
    int n = blockIdx.x * 4 + wave;
    if (n >= n_nodes) return;
    int d0 = lane * 4;
    float w[4], v0[4], v1[4], v2[4];
    #pragma unroll
    for (int j = 0; j < 4; j++) {
        w[j]  = loadf(w_att, d0 + j, isbf);
        v0[j] = b2f(e0[(size_t)n * 256 + d0 + j]);
        v1[j] = b2f(e1[(size_t)n * 256 + d0 + j]);
        v2[j] = b2f(e2[(size_t)n * 256 + d0 + j]);
    }
    float s0 = 0, s1 = 0, s2 = 0;
    #pragma unroll
    for (int j = 0; j < 4; j++) { s0 += v0[j] * w[j]; s1 += v1[j] * w[j]; s2 += v2[j] * w[j]; }
    for (int off = 1; off < 64; off <<= 1) {
        s0 += __shfl_xor(s0, off, 64);
        s1 += __shfl_xor(s1, off, 64);
        s2 += __shfl_xor(s2, off, 64);
    }
    float m = fmaxf(s0, fmaxf(s1, s2));
    float a0 = expf(s0 - m), a1 = expf(s1 - m), a2 = expf(s2 - m);
    float inv = 1.0f / (a0 + a1 + a2);
    a0 *= inv; a1 *= inv; a2 *= inv;
    #pragma unroll
    for (int j = 0; j < 4; j++) {
        float v = a0 * v0[j] + a1 * v1[j] + a2 * v2[j];
        if (isbf) ((bf16*)out)[(size_t)n * 256 + d0 + j] = f2b(v);
        else      ((float*)out)[(size_t)n * 256 + d0 + j] = v;
    }
}

// ---------------------------------------------------------------------------
extern "C" void kernel_launch(void* const* d_in, const int* in_sizes, int n_in,
                              void* d_out, int out_size, void* d_ws, size_t ws_size,
                              hipStream_t stream)
{
    (void)in_sizes; (void)n_in; (void)out_size; (void)ws_size;

    const void* init = d_in[0];
    const int*  ei[3] = {(const int*)d_in[1], (const int*)d_in[2], (const int*)d_in[3]};
    const void* ea[3] = {d_in[4], d_in[5], d_in[6]};
    const void* pW1 = d_in[7];
    const void* pb1 = d_in[8];
    const void* pW2 = d_in[9];
    const void* pb2 = d_in[10];
    const void* Wb[3] = {d_in[11], d_in[13], d_in[15]};
    const void* bb[3] = {d_in[12], d_in[14], d_in[16]};
    const void* w_att = d_in[17];

    char* ws = (char*)d_ws;
    size_t off = 0;
    auto carve = [&](size_t bytes) -> char* {
        off = (off + 255) & ~(size_t)255;
        char* p = ws + off; off += bytes; return p;
    };
    int*   flag  = (int*)carve(4);
    bf16*  WT    = (bf16*)carve((size_t)9 * 65536 * 2);
    bf16*  cembT = (bf16*)carve((size_t)D * M * 2);
    bf16*  x0    = (bf16*)carve(SEGEL * 2);
    int*   cnt   = (int*)carve((size_t)3 * N * 4);
    int*   colp  = (int*)carve((size_t)3 * (N + 1) * 4);
    float* dinv  = (float*)carve((size_t)3 * N * 4);
    float* nloop = (float*)carve((size_t)3 * N * 4);
    int*   srow  = (int*)carve((size_t)3 * E * 4);
    float* swv   = (float*)carve((size_t)3 * E * 4);
    bf16*  ybuf  = (bf16*)carve((size_t)3 * SEGEL * 2);
    bf16*  bufA  = (bf16*)carve((size_t)3 * SEGEL * 2);
    bf16*  bufB  = (bf16*)carve((size_t)3 * SEGEL * 2);
    // P (3*64*20000 ints = 15.36 MB) aliases bufB: only live during setup,
    // bufB first written as gemm output of layer 1 (after setup completes).
    int* P = (int*)bufB;

    detect_kernel<<<1, 64, 0, stream>>>(ea[0], flag);
    transpose_kernel<<<2304, 256, 0, stream>>>(Wb[0], Wb[1], Wb[2], WT, flag);
    col_embT_kernel<<<dim3(256, 4), 256, 0, stream>>>(pW1, pb1, pW2, pb2, cembT, flag);
    proj_gemm_kernel<<<625, 256, 0, stream>>>(init, cembT, x0, flag);

    countP_kernel<<<384, 256, 0, stream>>>(ei[0], ei[1], ei[2], P);
    cnt_sum_kernel<<<(3 * N + 255) / 256, 256, 0, stream>>>(P, cnt);
    scan_kernel<<<3, 1024, 0, stream>>>(cnt, colp);
    base_kernel<<<(3 * N + 255) / 256, 256, 0, stream>>>(P, colp);
    fill_kernel<<<384, 256, 0, stream>>>(ei[0], ei[1], ei[2], ea[0], ea[1], ea[2],
                                         P, srow, swv, flag);
    degsum_kernel<<<15000, 256, 0, stream>>>(colp, swv, dinv, nloop);
    snorm_kernel<<<15000, 256, 0, stream>>>(colp, srow, swv, dinv);

    const bf16 *i0 = x0, *i1 = x0, *i2 = x0;
    bf16* dsts[3] = {bufA, bufB, bufA};
    for (int l = 0; l < 3; l++) {
        aggregate_kernel<<<15000, 256, 0, stream>>>(i0, i1, i2, ybuf, colp, srow, swv, nloop);
        bf16* dst = dsts[l];
        gemm_relu_kernel<<<1875, 256, 0, stream>>>(ybuf, WT, l, bb[0], bb[1], bb[2],
                                                   dst, dst + SEGEL, dst + 2 * SEGEL, flag);
        i0 = dst; i1 = dst + SEGEL; i2 = dst + 2 * SEGEL;
    }
    attention_kernel<<<5000, 256, 0, stream>>>(bufA, bufA + SEGEL, bufA + 2 * SEGEL,
                                               w_att, d_out, N, flag);
}